// Round 2
// baseline (633.594 us; speedup 1.0000x reference)
//
#include <hip/hip_runtime.h>

// MPS chain: out[b,o] = vleft[b,:] . Mlabel_b[:,:,o] . rvec[b,:]
// Round 2: latency fixes on the round-1 structure.
//  - weights loaded via VECTOR path (pointer de-uniformed through __shfl) as
//    float4, so the scheduler can pipeline 512 B/site across unrolled sites.
//    Round 1 used s_load_dwordx16 x8/site with an exposed lgkmcnt(0) wait
//    every site (~3400 stall cyc/site, VALUBusy 5.7%).
//  - x staged through LDS in 16-site chunks, TRANSPOSED xs[s][lane]:
//    the 64-line per-instruction gather is paid 4x/chunk instead of 16x,
//    and per-site x reads are stride-1 conflict-free LDS broadcasts.
// Block 128 = 2 waves (wave0 left chains, wave1 right chains, 64 batches),
// grid 256 = 1 block/CU. fp32 throughout (precision threshold).

#define BATCH   16384
#define NSITES  784
#define DIM     8
#define ODIM    10
#define LABEL   392

__device__ __forceinline__ const float* make_divergent(const float* p) {
    // Route the pointer through lanes so uniformity analysis marks it
    // divergent -> global_load_dwordx4 (VGPR-prefetchable) instead of s_load.
    long long a = (long long)p;
    a = __shfl(a, 0, 64);
    return (const float*)a;
}

// Stage 16 sites x 64 batches of x into xs[s][lane] (transposed).
// lane = 4*r + j: loads float4 (sites c0+4j..c0+4j+3) of batch row pass*16+r.
// Global side: 16 batch rows x 64B per instruction (coalesced within rows).
// LDS write: 4-way bank conflict (cheap, 16 writes/chunk); reads conflict-free.
__device__ __forceinline__ void stage_x(const float* __restrict__ x, int base, int c0,
                                        float xsw[16][64], int lane) {
    const int j  = lane & 3;
    const int r0 = lane >> 2;
    #pragma unroll
    for (int pass = 0; pass < 4; ++pass) {
        const int row = pass * 16 + r0;
        const float4 t = *(const float4*)(x + (size_t)(base + row) * NSITES + c0 + 4 * j);
        xsw[4 * j + 0][row] = t.x;
        xsw[4 * j + 1][row] = t.y;
        xsw[4 * j + 2][row] = t.z;
        xsw[4 * j + 3][row] = t.w;
    }
}

// v <- v^T M_i with M[d][f][e] (128 floats), phi = (1-p, p)
__device__ __forceinline__ void step_left(float v[DIM], const float* __restrict__ w, float p) {
    const float q = 1.0f - p;
    float a0[DIM], a1[DIM];
    #pragma unroll
    for (int e = 0; e < DIM; ++e) { a0[e] = 0.f; a1[e] = 0.f; }
    #pragma unroll
    for (int d = 0; d < DIM; ++d) {
        const float4 wa = *(const float4*)(w + d * 16 + 0);
        const float4 wb = *(const float4*)(w + d * 16 + 4);
        const float4 wc = *(const float4*)(w + d * 16 + 8);
        const float4 we = *(const float4*)(w + d * 16 + 12);
        const float vd = v[d];
        a0[0] = fmaf(vd, wa.x, a0[0]); a0[1] = fmaf(vd, wa.y, a0[1]);
        a0[2] = fmaf(vd, wa.z, a0[2]); a0[3] = fmaf(vd, wa.w, a0[3]);
        a0[4] = fmaf(vd, wb.x, a0[4]); a0[5] = fmaf(vd, wb.y, a0[5]);
        a0[6] = fmaf(vd, wb.z, a0[6]); a0[7] = fmaf(vd, wb.w, a0[7]);
        a1[0] = fmaf(vd, wc.x, a1[0]); a1[1] = fmaf(vd, wc.y, a1[1]);
        a1[2] = fmaf(vd, wc.z, a1[2]); a1[3] = fmaf(vd, wc.w, a1[3]);
        a1[4] = fmaf(vd, we.x, a1[4]); a1[5] = fmaf(vd, we.y, a1[5]);
        a1[6] = fmaf(vd, we.z, a1[6]); a1[7] = fmaf(vd, we.w, a1[7]);
    }
    #pragma unroll
    for (int e = 0; e < DIM; ++e) v[e] = fmaf(q, a0[e], p * a1[e]);
}

// r <- M_i r
__device__ __forceinline__ void step_right(float r[DIM], const float* __restrict__ w, float p) {
    const float q = 1.0f - p;
    float rn[DIM];
    #pragma unroll
    for (int d = 0; d < DIM; ++d) {
        const float4 wa = *(const float4*)(w + d * 16 + 0);
        const float4 wb = *(const float4*)(w + d * 16 + 4);
        const float4 wc = *(const float4*)(w + d * 16 + 8);
        const float4 we = *(const float4*)(w + d * 16 + 12);
        float a0 = wa.x * r[0];
        a0 = fmaf(wa.y, r[1], a0); a0 = fmaf(wa.z, r[2], a0); a0 = fmaf(wa.w, r[3], a0);
        a0 = fmaf(wb.x, r[4], a0); a0 = fmaf(wb.y, r[5], a0);
        a0 = fmaf(wb.z, r[6], a0); a0 = fmaf(wb.w, r[7], a0);
        float a1 = wc.x * r[0];
        a1 = fmaf(wc.y, r[1], a1); a1 = fmaf(wc.z, r[2], a1); a1 = fmaf(wc.w, r[3], a1);
        a1 = fmaf(we.x, r[4], a1); a1 = fmaf(we.y, r[5], a1);
        a1 = fmaf(we.z, r[6], a1); a1 = fmaf(we.w, r[7], a1);
        rn[d] = fmaf(q, a0, p * a1);
    }
    #pragma unroll
    for (int d = 0; d < DIM; ++d) r[d] = rn[d];
}

__global__ __launch_bounds__(128, 1) void mps_chain_kernel(
    const float* __restrict__ x,      // [B, N]
    const float* __restrict__ w0,     // [2, D]
    const float* __restrict__ Wl,     // [391, D, 2, D]
    const float* __restrict__ wlab,   // [D, 2, D, O]
    const float* __restrict__ Wr,     // [390, D, 2, D]
    const float* __restrict__ wlast,  // [D, 2]
    float* __restrict__ out)          // [B, O]
{
    __shared__ float xs[2][16][64];   // per-wave x staging, transposed
    __shared__ float vl[64][DIM];
    __shared__ float rv[64][DIM];

    const int lane = threadIdx.x & 63;
    const int wave = threadIdx.x >> 6;
    const int base = blockIdx.x * 64;

    if (wave == 0) {
        const float* W = make_divergent(Wl);
        float v[DIM];
        stage_x(x, base, 0, xs[0], lane);
        {
            const float p = xs[0][0][lane];
            const float q = 1.0f - p;
            #pragma unroll
            for (int d = 0; d < DIM; ++d)
                v[d] = fmaf(q, w0[d], p * w0[DIM + d]);
        }
        #pragma unroll 4
        for (int s = 1; s < 16; ++s)                       // sites 1..15
            step_left(v, W + (size_t)(s - 1) * 128, xs[0][s][lane]);
        #pragma unroll 1
        for (int c0 = 16; c0 <= 368; c0 += 16) {           // sites 16..383
            stage_x(x, base, c0, xs[0], lane);
            #pragma unroll 4
            for (int s = 0; s < 16; ++s)
                step_left(v, W + (size_t)(c0 + s - 1) * 128, xs[0][s][lane]);
        }
        stage_x(x, base, 384, xs[0], lane);
        #pragma unroll 4
        for (int s = 0; s < 8; ++s)                        // sites 384..391
            step_left(v, W + (size_t)(384 + s - 1) * 128, xs[0][s][lane]);
        #pragma unroll
        for (int d = 0; d < DIM; ++d) vl[lane][d] = v[d];
    } else {
        const float* W = make_divergent(Wr);
        float r[DIM];
        stage_x(x, base, 768, xs[1], lane);
        {
            const float p = xs[1][15][lane];               // site 783
            const float q = 1.0f - p;
            #pragma unroll
            for (int d = 0; d < DIM; ++d)
                r[d] = fmaf(q, wlast[d * 2], p * wlast[d * 2 + 1]);
        }
        #pragma unroll 4
        for (int s = 14; s >= 0; --s)                      // sites 782..768
            step_right(r, W + (size_t)(768 + s - 393) * 128, xs[1][s][lane]);
        #pragma unroll 1
        for (int c0 = 752; c0 >= 400; c0 -= 16) {          // sites 767..400
            stage_x(x, base, c0, xs[1], lane);
            #pragma unroll 4
            for (int s = 15; s >= 0; --s)
                step_right(r, W + (size_t)(c0 + s - 393) * 128, xs[1][s][lane]);
        }
        stage_x(x, base, 384, xs[1], lane);
        #pragma unroll 4
        for (int s = 15; s >= 9; --s)                      // sites 399..393
            step_right(r, W + (size_t)(384 + s - 393) * 128, xs[1][s][lane]);
        #pragma unroll
        for (int d = 0; d < DIM; ++d) rv[lane][d] = r[d];
    }

    __syncthreads();

    // ---- label-site combine: out[o] = sum_{d,e} vl[d] * Mlab[d,e,o] * rv[e]
    {
        const int bb = threadIdx.x & 63;
        const int oh = threadIdx.x >> 6;          // 0 -> o 0..4, 1 -> o 5..9
        const int b2 = base + bb;
        const float p = x[(size_t)b2 * NSITES + LABEL];
        const float q = 1.0f - p;

        float vv[DIM], rr[DIM];
        #pragma unroll
        for (int d = 0; d < DIM; ++d) { vv[d] = vl[bb][d]; rr[d] = rv[bb][d]; }

        float acc[5];
        #pragma unroll
        for (int k = 0; k < 5; ++k) acc[k] = 0.0f;

        #pragma unroll
        for (int d = 0; d < DIM; ++d) {
            #pragma unroll
            for (int e = 0; e < DIM; ++e) {
                const float z = vv[d] * rr[e];
                const float* w0p = wlab + ((size_t)(d * 2 + 0) * DIM + e) * ODIM + oh * 5;
                const float* w1p = wlab + ((size_t)(d * 2 + 1) * DIM + e) * ODIM + oh * 5;
                #pragma unroll
                for (int k = 0; k < 5; ++k) {
                    const float m = fmaf(p, w1p[k], q * w0p[k]);
                    acc[k] = fmaf(z, m, acc[k]);
                }
            }
        }
        #pragma unroll
        for (int k = 0; k < 5; ++k)
            out[(size_t)b2 * ODIM + oh * 5 + k] = acc[k];
    }
}

extern "C" void kernel_launch(void* const* d_in, const int* in_sizes, int n_in,
                              void* d_out, int out_size, void* d_ws, size_t ws_size,
                              hipStream_t stream) {
    const float* x     = (const float*)d_in[0];
    const float* w0    = (const float*)d_in[1];
    const float* Wl    = (const float*)d_in[2];
    const float* wlab  = (const float*)d_in[3];
    const float* Wr    = (const float*)d_in[4];
    const float* wlast = (const float*)d_in[5];
    float* out = (float*)d_out;

    mps_chain_kernel<<<BATCH / 64, 128, 0, stream>>>(x, w0, Wl, wlab, Wr, wlast, out);
}

// Round 3
// 461.837 us; speedup vs baseline: 1.3719x; 1.3719x over previous
//
#include <hip/hip_runtime.h>

// Round 3: lane-parallel bond dimension.
// out[b,o] = vleft[b,:] . Mlabel_b[:,:,o] . rvec[b,:]
//
// Decomposition: 8 lanes per (batch, chain); lane e owns element e of the
// running bond vector. Per site each lane loads 16 contiguous weights
// (4x float4) instead of the whole 128-float site matrix (32x float4 in
// rounds 1-2 -- which serialized at ~200cyc/load with only 2 waves/CU).
// The left chain needs W transposed for contiguity, done by a tiny pre-pass
// into d_ws. Cross-lane v broadcast: per-group LDS buffer (write 1 float,
// read back 8 via 2x b128; same-wave, no barrier needed).
//
// Block 256 = 16 batches x {left,right} x 8 lanes; grid 1024
// -> 4 blocks/CU, 16 waves/CU, 4 waves/SIMD (vs 2 waves/CU in rounds 1-2).

#define NSITES 784
#define DIM    8
#define ODIM   10
#define LABEL  392
#define L_LEFT 391

// WlT[i][e][f][d] = Wl[i][d][f][e]  (so lane e reads contiguous [e][f][0..7])
__global__ __launch_bounds__(128) void transpose_wl(const float* __restrict__ Wl,
                                                    float* __restrict__ WlT) {
    const int i = blockIdx.x;          // site 0..390
    const int t = threadIdx.x;         // 0..127
    const int d = t >> 4;
    const int f = (t >> 3) & 1;
    const int e = t & 7;
    WlT[i * 128 + e * 16 + f * 8 + d] = Wl[i * 128 + d * 16 + f * 8 + e];
}

__global__ __launch_bounds__(256, 1) void mps_main(
    const float* __restrict__ x,      // [B, N]
    const float* __restrict__ w0,     // [2, D]
    const float* __restrict__ WlT,    // [391, D(e), 2, D(d)]  transposed
    const float* __restrict__ wlab,   // [D, 2, D, O]
    const float* __restrict__ Wr,     // [390, D, 2, D]
    const float* __restrict__ wlast,  // [D, 2]
    float* __restrict__ out)          // [B, O]
{
    __shared__ float vbuf[32][8];     // per-group broadcast buffer (same-wave only)
    __shared__ float vl[16][8];
    __shared__ float rv[16][8];

    const int tid  = threadIdx.x;
    const int g    = tid >> 3;        // group 0..31
    const int e    = tid & 7;         // owned bond index
    const int half = g >> 4;          // 0 = left chain, 1 = right chain
    const int bb   = g & 15;          // batch within block
    const int b    = blockIdx.x * 16 + bb;
    const float* xr = x + (size_t)b * NSITES;

    if (half == 0) {
        // ---- left chain: v_new[e] = sum_f phi_f sum_d v[d] * Wl[d][f][e]
        //                           = sum_f phi_f sum_d WlT[e][f][d] * v[d]
        float p = xr[0];
        float v = fmaf(1.0f - p, w0[e], p * w0[DIM + e]);
        const float* wt = WlT + e * 16;
        #pragma unroll 2
        for (int i = 1; i <= L_LEFT; ++i) {
            vbuf[g][e] = v;
            const float4 w00 = *(const float4*)(wt + 0);   // [e][0][0..3]
            const float4 w01 = *(const float4*)(wt + 4);   // [e][0][4..7]
            const float4 w10 = *(const float4*)(wt + 8);   // [e][1][0..3]
            const float4 w11 = *(const float4*)(wt + 12);  // [e][1][4..7]
            const float4 va  = *(const float4*)&vbuf[g][0];
            const float4 vb  = *(const float4*)&vbuf[g][4];
            const float pi = xr[i];
            const float qi = 1.0f - pi;
            float a0 = va.x * w00.x;
            a0 = fmaf(va.y, w00.y, a0); a0 = fmaf(va.z, w00.z, a0); a0 = fmaf(va.w, w00.w, a0);
            a0 = fmaf(vb.x, w01.x, a0); a0 = fmaf(vb.y, w01.y, a0);
            a0 = fmaf(vb.z, w01.z, a0); a0 = fmaf(vb.w, w01.w, a0);
            float a1 = va.x * w10.x;
            a1 = fmaf(va.y, w10.y, a1); a1 = fmaf(va.z, w10.z, a1); a1 = fmaf(va.w, w10.w, a1);
            a1 = fmaf(vb.x, w11.x, a1); a1 = fmaf(vb.y, w11.y, a1);
            a1 = fmaf(vb.z, w11.z, a1); a1 = fmaf(vb.w, w11.w, a1);
            v = fmaf(qi, a0, pi * a1);
            wt += 128;
        }
        vl[bb][e] = v;
    } else {
        // ---- right chain (backward): r_new[d] = sum_f phi_f sum_e Wr[d][f][e] * r[e]
        // lane owns output index d == e variable here; loads are contiguous natively.
        float p = xr[NSITES - 1];
        float r = fmaf(1.0f - p, wlast[e * 2], p * wlast[e * 2 + 1]);
        const float* wr = Wr + (size_t)(NSITES - 2 - (LABEL + 1)) * 128 + e * 16;
        #pragma unroll 2
        for (int i = NSITES - 2; i > LABEL; --i) {
            vbuf[g][e] = r;
            const float4 w00 = *(const float4*)(wr + 0);   // [d][0][0..3]
            const float4 w01 = *(const float4*)(wr + 4);   // [d][0][4..7]
            const float4 w10 = *(const float4*)(wr + 8);   // [d][1][0..3]
            const float4 w11 = *(const float4*)(wr + 12);  // [d][1][4..7]
            const float4 ra  = *(const float4*)&vbuf[g][0];
            const float4 rb  = *(const float4*)&vbuf[g][4];
            const float pi = xr[i];
            const float qi = 1.0f - pi;
            float b0 = ra.x * w00.x;
            b0 = fmaf(ra.y, w00.y, b0); b0 = fmaf(ra.z, w00.z, b0); b0 = fmaf(ra.w, w00.w, b0);
            b0 = fmaf(rb.x, w01.x, b0); b0 = fmaf(rb.y, w01.y, b0);
            b0 = fmaf(rb.z, w01.z, b0); b0 = fmaf(rb.w, w01.w, b0);
            float b1 = ra.x * w10.x;
            b1 = fmaf(ra.y, w10.y, b1); b1 = fmaf(ra.z, w10.z, b1); b1 = fmaf(ra.w, w10.w, b1);
            b1 = fmaf(rb.x, w11.x, b1); b1 = fmaf(rb.y, w11.y, b1);
            b1 = fmaf(rb.z, w11.z, b1); b1 = fmaf(rb.w, w11.w, b1);
            r = fmaf(qi, b0, pi * b1);
            wr -= 128;
        }
        rv[bb][e] = r;
    }

    __syncthreads();

    // ---- label-site combine: out[b,o] = sum_{d,e} vl[d] * Mlab[d,e,o] * rv[e]
    if (tid < 16 * ODIM) {
        const int bb2 = tid / ODIM;
        const int o   = tid - bb2 * ODIM;
        const int b2  = blockIdx.x * 16 + bb2;
        const float p = x[(size_t)b2 * NSITES + LABEL];
        const float q = 1.0f - p;
        float acc = 0.0f;
        #pragma unroll
        for (int d = 0; d < DIM; ++d) {
            const float vd = vl[bb2][d];
            #pragma unroll
            for (int ee = 0; ee < DIM; ++ee) {
                const float z = vd * rv[bb2][ee];
                const float m = fmaf(q, wlab[((d * 2 + 0) * DIM + ee) * ODIM + o],
                                     p * wlab[((d * 2 + 1) * DIM + ee) * ODIM + o]);
                acc = fmaf(z, m, acc);
            }
        }
        out[(size_t)b2 * ODIM + o] = acc;
    }
}

extern "C" void kernel_launch(void* const* d_in, const int* in_sizes, int n_in,
                              void* d_out, int out_size, void* d_ws, size_t ws_size,
                              hipStream_t stream) {
    const float* x     = (const float*)d_in[0];
    const float* w0    = (const float*)d_in[1];
    const float* Wl    = (const float*)d_in[2];
    const float* wlab  = (const float*)d_in[3];
    const float* Wr    = (const float*)d_in[4];
    const float* wlast = (const float*)d_in[5];
    float* out = (float*)d_out;
    float* WlT = (float*)d_ws;                 // 391*128*4 = 200 KB scratch

    transpose_wl<<<L_LEFT, 128, 0, stream>>>(Wl, WlT);
    mps_main<<<16384 / 16, 256, 0, stream>>>(x, w0, WlT, wlab, Wr, wlast, out);
}

// Round 4
// 202.665 us; speedup vs baseline: 3.1263x; 2.2788x over previous
//
#include <hip/hip_runtime.h>

// Round 4: LDS-staged weights, double-buffered.
// out[b,o] = vleft[b,:] . Mlabel_b[:,:,o] . rvec[b,:]
//
// Round-3 diagnosis: 2455 cyc/site/wave vs ~600 cyc of raw latency -- the
// gap is TA/L1 line-lookup throughput: 16 waves/CU x 5 VMEM instr/site,
// each spanning 8 cache lines (~640 lookups/site/CU), all redundant across
// waves, plus a zero-prefetch schedule (VGPR=32).
// Fix: block = 32 batches x ONE side x 8 lanes (256 thr). Weights + x staged
// into LDS in 16-site chunks, double-buffered; all per-site reads become
// ds_read_b128/b32. Padded weight layout (e-stride 20 words) keeps 16B
// alignment AND makes each b128 read hit all 32 banks exactly once.
// Left/right boundary vectors -> d_ws; third kernel combines at the label.

#define NSITES 784
#define DIM    8
#define ODIM   10
#define LABEL  392
#define L_LEFT 391   // sites 1..391,  weights Wl[0..390]
#define L_RIGHT 390  // sites 393..782, weights Wr[0..389]

#define WST 160      // words per staged site: 8 lanes * 20-word stride

__device__ __forceinline__ float dot8(const float4& a, const float4& b,
                                      const float4& wa, const float4& wb) {
    float t = a.x * wa.x;
    t = fmaf(a.y, wa.y, t); t = fmaf(a.z, wa.z, t); t = fmaf(a.w, wa.w, t);
    t = fmaf(b.x, wb.x, t); t = fmaf(b.y, wb.y, t);
    t = fmaf(b.z, wb.z, t); t = fmaf(b.w, wb.w, t);
    return t;
}

// WlT[i][e][f][d] = Wl[i][d][f][e]  (lane e reads contiguous 16 floats)
__global__ __launch_bounds__(128) void transpose_wl(const float* __restrict__ Wl,
                                                    float* __restrict__ WlT) {
    const int i = blockIdx.x;
    const int t = threadIdx.x;
    const int d = t >> 4;
    const int f = (t >> 3) & 1;
    const int e = t & 7;
    WlT[i * 128 + e * 16 + f * 8 + d] = Wl[i * 128 + d * 16 + f * 8 + e];
}

__global__ __launch_bounds__(256, 1) void mps_main(
    const float* __restrict__ x,      // [B, N]
    const float* __restrict__ w0,     // [2, D]
    const float* __restrict__ WlT,    // [391, e, f, d]
    const float* __restrict__ Wr,     // [390, d, f, e]
    const float* __restrict__ wlast,  // [D, 2]
    float* __restrict__ VL,           // [B, 8] workspace
    float* __restrict__ RV)           // [B, 8] workspace
{
    __shared__ float wb[2][16 * WST];   // staged weights, padded
    __shared__ float xb[2][16 * 32];    // staged x, [site][batch]
    __shared__ float vbuf[32][8];       // per-group bond-vector exchange

    const int tid  = threadIdx.x;
    const int side = blockIdx.x >> 9;   // 0 = left, 1 = right
    const int tile = blockIdx.x & 511;
    const int b0   = tile * 32;
    const int g    = tid >> 3;          // batch within tile (0..31)
    const int e    = tid & 7;           // owned bond index
    const float* Wsrc = side ? Wr : WlT;

    // stage chunk c into buffer `buf`: weight sites + x values, slot s = 0..15
    auto stage = [&](int buf, int c) {
        #pragma unroll
        for (int r = 0; r < 2; ++r) {
            const int cid = tid + 256 * r;          // 0..511
            const int s   = cid >> 5;               // site slot
            const int u   = cid & 31;
            const int e2  = u >> 2;
            const int k   = u & 3;
            const int wi  = side == 0 ? (c * 16 + s) : (389 - c * 16 - s);
            const bool ok = side == 0 ? (wi < L_LEFT) : (wi >= 0);
            if (ok) {
                const float4 w = *(const float4*)(Wsrc + (size_t)wi * 128 + e2 * 16 + k * 4);
                *(float4*)&wb[buf][s * WST + e2 * 20 + k * 4] = w;
            }
        }
        #pragma unroll
        for (int r = 0; r < 2; ++r) {
            const int cid = tid + 256 * r;
            const int s   = cid >> 5;
            const int g2  = cid & 31;
            const int xi  = side == 0 ? (1 + c * 16 + s) : (782 - c * 16 - s);
            const bool ok = side == 0 ? (xi <= L_LEFT) : (xi > LABEL);
            if (ok) xb[buf][s * 32 + g2] = x[(size_t)(b0 + g2) * NSITES + xi];
        }
    };

    // boundary init
    float v;
    if (side == 0) {
        const float p = x[(size_t)(b0 + g) * NSITES + 0];
        v = fmaf(1.0f - p, w0[e], p * w0[DIM + e]);
    } else {
        const float p = x[(size_t)(b0 + g) * NSITES + (NSITES - 1)];
        v = fmaf(1.0f - p, wlast[e * 2], p * wlast[e * 2 + 1]);
    }

    stage(0, 0);
    int buf = 0;

    #pragma unroll 1
    for (int c = 0; c < 24; ++c) {                    // 24 full chunks = 384 sites
        __syncthreads();
        stage(buf ^ 1, c + 1);
        const float* wbp = &wb[buf][e * 20];
        const float* xbp = &xb[buf][g];
        #pragma unroll
        for (int j = 0; j < 16; ++j) {
            vbuf[g][e] = v;
            const float  p   = xbp[j * 32];
            const float4 w00 = *(const float4*)(wbp + j * WST + 0);
            const float4 w01 = *(const float4*)(wbp + j * WST + 4);
            const float4 w10 = *(const float4*)(wbp + j * WST + 8);
            const float4 w11 = *(const float4*)(wbp + j * WST + 12);
            const float4 va  = *(const float4*)&vbuf[g][0];
            const float4 vb2 = *(const float4*)&vbuf[g][4];
            const float a0 = dot8(va, vb2, w00, w01);
            const float a1 = dot8(va, vb2, w10, w11);
            v = fmaf(1.0f - p, a0, p * a1);
        }
        buf ^= 1;
    }
    __syncthreads();

    // tail: 7 sites (left) / 6 sites (right), staged as chunk 24
    {
        const int tl = side == 0 ? 7 : 6;
        const float* wbp = &wb[buf][e * 20];
        const float* xbp = &xb[buf][g];
        #pragma unroll 7
        for (int j = 0; j < tl; ++j) {
            vbuf[g][e] = v;
            const float  p   = xbp[j * 32];
            const float4 w00 = *(const float4*)(wbp + j * WST + 0);
            const float4 w01 = *(const float4*)(wbp + j * WST + 4);
            const float4 w10 = *(const float4*)(wbp + j * WST + 8);
            const float4 w11 = *(const float4*)(wbp + j * WST + 12);
            const float4 va  = *(const float4*)&vbuf[g][0];
            const float4 vb2 = *(const float4*)&vbuf[g][4];
            const float a0 = dot8(va, vb2, w00, w01);
            const float a1 = dot8(va, vb2, w10, w11);
            v = fmaf(1.0f - p, a0, p * a1);
        }
    }

    float* dst = side == 0 ? VL : RV;
    dst[(size_t)(b0 + g) * DIM + e] = v;
}

__global__ __launch_bounds__(256) void mps_combine(
    const float* __restrict__ x,
    const float* __restrict__ wlab,   // [D, 2, D, O]
    const float* __restrict__ VL,
    const float* __restrict__ RV,
    float* __restrict__ out)
{
    const int idx = blockIdx.x * 256 + threadIdx.x;   // 0..163839 exactly
    const int b   = idx / ODIM;
    const int o   = idx - b * ODIM;
    const float p = x[(size_t)b * NSITES + LABEL];
    const float q = 1.0f - p;

    float vl[DIM], rv[DIM];
    #pragma unroll
    for (int d = 0; d < DIM; ++d) { vl[d] = VL[b * DIM + d]; rv[d] = RV[b * DIM + d]; }

    float acc = 0.0f;
    #pragma unroll
    for (int d = 0; d < DIM; ++d) {
        #pragma unroll
        for (int ee = 0; ee < DIM; ++ee) {
            const float m = fmaf(q, wlab[((d * 2 + 0) * DIM + ee) * ODIM + o],
                                 p * wlab[((d * 2 + 1) * DIM + ee) * ODIM + o]);
            acc = fmaf(vl[d] * rv[ee], m, acc);
        }
    }
    out[idx] = acc;
}

extern "C" void kernel_launch(void* const* d_in, const int* in_sizes, int n_in,
                              void* d_out, int out_size, void* d_ws, size_t ws_size,
                              hipStream_t stream) {
    const float* x     = (const float*)d_in[0];
    const float* w0    = (const float*)d_in[1];
    const float* Wl    = (const float*)d_in[2];
    const float* wlab  = (const float*)d_in[3];
    const float* Wr    = (const float*)d_in[4];
    const float* wlast = (const float*)d_in[5];
    float* out = (float*)d_out;

    float* WlT = (float*)d_ws;                 // 391*128 floats
    float* VL  = WlT + L_LEFT * 128;           // 16384*8 floats
    float* RV  = VL + 16384 * DIM;             // 16384*8 floats  (~1.25 MB total)

    transpose_wl<<<L_LEFT, 128, 0, stream>>>(Wl, WlT);
    mps_main<<<1024, 256, 0, stream>>>(x, w0, WlT, Wr, wlast, VL, RV);
    mps_combine<<<16384 * ODIM / 256, 256, 0, stream>>>(x, wlab, VL, RV, out);
}

// Round 5
// 195.007 us; speedup vs baseline: 3.2491x; 1.0393x over previous
//
#include <hip/hip_runtime.h>

// Round 5: same decomposition as round 4 (8 lanes per (batch,chain), LDS
// double-buffered weights), with the three measured leaks fixed:
//  1) per-site LDS address math -> 0: fixed base VGPRs + compile-time
//     offset immediates (site j at byte offset j*640 within the staged chunk).
//  2) vbuf bank conflicts -> 0: group stride 12 words; the 8 groups' b128
//     reads tile all 32 banks exactly once (round 4's stride 8 was 4-way).
//  3) kernel count 3 -> 2: Wl transpose folded into LDS staging; combine
//     kernel stages wlab in LDS. (~78 us of round-4 total was outside mps_main.)
// Block 256 = 32 batches x one side x 8 lanes; grid 1024 -> 4 blocks/CU,
// 16 waves/CU. fp32 throughout.

#define NSITES 784
#define DIM    8
#define ODIM   10
#define LABEL  392
#define WST    160   // words per staged site: 8 slices * 20-word stride
#define VST    12    // vbuf group stride in words (bank-tiling)

__device__ __forceinline__ float dot8(const float4& a, const float4& b,
                                      const float4& wa, const float4& wb) {
    float t = a.x * wa.x;
    t = fmaf(a.y, wa.y, t); t = fmaf(a.z, wa.z, t); t = fmaf(a.w, wa.w, t);
    t = fmaf(b.x, wb.x, t); t = fmaf(b.y, wb.y, t);
    t = fmaf(b.z, wb.z, t); t = fmaf(b.w, wb.w, t);
    return t;
}

__global__ __launch_bounds__(256, 4) void mps_main(
    const float* __restrict__ x,      // [B, N]
    const float* __restrict__ w0,     // [2, D]
    const float* __restrict__ Wl,     // [391, d, f, e]  (original layout)
    const float* __restrict__ Wr,     // [390, d, f, e]
    const float* __restrict__ wlast,  // [D, 2]
    float* __restrict__ VL,           // [B, 8]
    float* __restrict__ RV)           // [B, 8]
{
    __shared__ float wb[2][16 * WST];   // 2 x 10 KB staged weights (padded)
    __shared__ float xb[2][16 * 32];    // 2 x 2 KB staged x, [site][batch]
    __shared__ float vbuf[32 * VST];    // bond-vector exchange, stride-12

    const int tid  = threadIdx.x;
    const int side = blockIdx.x >> 9;   // 0 = left chain, 1 = right chain
    const int tile = blockIdx.x & 511;
    const int b0   = tile * 32;
    const int g    = tid >> 3;          // batch group 0..31
    const int e    = tid & 7;           // owned bond index

    // Stage chunk c (16 sites) into buffer `buf`. nt < 16 only for the tail.
    // Left side: transpose Wl[d][f][e] -> wb[e][f][d] on the fly.
    // Right side: direct padded copy (lane's slice is already contiguous).
    auto stage = [&](int buf, int c, int nt) {
        if (side == 0) {
            #pragma unroll
            for (int r = 0; r < 2; ++r) {
                const int cid = tid + 256 * r;        // 0..511
                const int s   = cid >> 5;             // site slot
                const int u   = cid & 31;
                const int d   = u >> 2;
                const int f   = (u >> 1) & 1;
                const int h   = u & 1;                // e-half
                if (s < nt) {
                    const float4 w = *(const float4*)(Wl + (size_t)(c * 16 + s) * 128 + d * 16 + f * 8 + h * 4);
                    float* dst = &wb[buf][s * WST + f * 8 + d];
                    dst[(4 * h + 0) * 20] = w.x;
                    dst[(4 * h + 1) * 20] = w.y;
                    dst[(4 * h + 2) * 20] = w.z;
                    dst[(4 * h + 3) * 20] = w.w;
                }
            }
            #pragma unroll
            for (int r = 0; r < 2; ++r) {
                const int cid = tid + 256 * r;
                const int s   = cid >> 5;
                const int g2  = cid & 31;
                if (s < nt)
                    xb[buf][s * 32 + g2] = x[(size_t)(b0 + g2) * NSITES + 1 + c * 16 + s];
            }
        } else {
            #pragma unroll
            for (int r = 0; r < 2; ++r) {
                const int cid = tid + 256 * r;
                const int s   = cid >> 5;
                const int u   = cid & 31;
                const int d   = u >> 2;
                const int k   = u & 3;
                if (s < nt) {
                    const float4 w = *(const float4*)(Wr + (size_t)(389 - c * 16 - s) * 128 + u * 4);
                    *(float4*)&wb[buf][s * WST + d * 20 + k * 4] = w;
                }
            }
            #pragma unroll
            for (int r = 0; r < 2; ++r) {
                const int cid = tid + 256 * r;
                const int s   = cid >> 5;
                const int g2  = cid & 31;
                if (s < nt)
                    xb[buf][s * 32 + g2] = x[(size_t)(b0 + g2) * NSITES + 782 - c * 16 - s];
            }
        }
    };

    // boundary init
    float v;
    if (side == 0) {
        const float p = x[(size_t)(b0 + g) * NSITES + 0];
        v = fmaf(1.0f - p, w0[e], p * w0[DIM + e]);
    } else {
        const float p = x[(size_t)(b0 + g) * NSITES + (NSITES - 1)];
        v = fmaf(1.0f - p, wlast[e * 2], p * wlast[e * 2 + 1]);
    }

    stage(0, 0, 16);
    int buf = 0;

    // loop-invariant LDS bases; per-site access via offset immediates only
    const float* wp0 = &wb[0][e * 20];
    const float* wp1 = &wb[1][e * 20];
    const float* xp0 = &xb[0][g];
    const float* xp1 = &xb[1][g];
    float* vw = &vbuf[g * VST + e];
    const float* vr = &vbuf[g * VST];

    #pragma unroll 1
    for (int c = 0; c < 24; ++c) {                 // 24 full chunks = 384 sites
        __syncthreads();                           // chunk c staged; buf^1 free
        if (c < 23) stage(buf ^ 1, c + 1, 16);
        else        stage(buf ^ 1, 24, side == 0 ? 7 : 6);   // tail chunk
        const float* wp = buf ? wp1 : wp0;
        const float* xp = buf ? xp1 : xp0;
        #pragma unroll
        for (int j = 0; j < 16; ++j) {
            *vw = v;
            const float  p   = xp[j * 32];
            const float4 w00 = *(const float4*)(wp + j * WST + 0);
            const float4 w01 = *(const float4*)(wp + j * WST + 4);
            const float4 w10 = *(const float4*)(wp + j * WST + 8);
            const float4 w11 = *(const float4*)(wp + j * WST + 12);
            const float4 va  = *(const float4*)(vr + 0);
            const float4 vb2 = *(const float4*)(vr + 4);
            const float a0 = dot8(va, vb2, w00, w01);
            const float a1 = dot8(va, vb2, w10, w11);
            v = fmaf(1.0f - p, a0, p * a1);
        }
        buf ^= 1;
    }

    __syncthreads();                               // tail staged
    {
        const int nt = side == 0 ? 7 : 6;
        const float* wp = buf ? wp1 : wp0;
        const float* xp = buf ? xp1 : xp0;
        for (int j = 0; j < nt; ++j) {
            *vw = v;
            const float  p   = xp[j * 32];
            const float4 w00 = *(const float4*)(wp + j * WST + 0);
            const float4 w01 = *(const float4*)(wp + j * WST + 4);
            const float4 w10 = *(const float4*)(wp + j * WST + 8);
            const float4 w11 = *(const float4*)(wp + j * WST + 12);
            const float4 va  = *(const float4*)(vr + 0);
            const float4 vb2 = *(const float4*)(vr + 4);
            const float a0 = dot8(va, vb2, w00, w01);
            const float a1 = dot8(va, vb2, w10, w11);
            v = fmaf(1.0f - p, a0, p * a1);
        }
    }

    float* dst = side == 0 ? VL : RV;
    dst[(size_t)(b0 + g) * DIM + e] = v;
}

__global__ __launch_bounds__(256) void mps_combine(
    const float* __restrict__ x,
    const float* __restrict__ wlab,   // [D, 2, D, O] = 1280 floats
    const float* __restrict__ VL,
    const float* __restrict__ RV,
    float* __restrict__ out)
{
    __shared__ float wl[1280];
    for (int k = threadIdx.x; k < 320; k += 256)
        *(float4*)&wl[k * 4] = *(const float4*)&wlab[k * 4];
    __syncthreads();

    const int idx = blockIdx.x * 256 + threadIdx.x;   // 0..163839 exactly
    const int b   = idx / ODIM;
    const int o   = idx - b * ODIM;
    const float p = x[(size_t)b * NSITES + LABEL];
    const float q = 1.0f - p;

    float vl[DIM], rv[DIM];
    #pragma unroll
    for (int d = 0; d < DIM; d += 4) {
        *(float4*)&vl[d] = *(const float4*)&VL[(size_t)b * DIM + d];
        *(float4*)&rv[d] = *(const float4*)&RV[(size_t)b * DIM + d];
    }

    float acc = 0.0f;
    #pragma unroll
    for (int d = 0; d < DIM; ++d) {
        #pragma unroll
        for (int ee = 0; ee < DIM; ++ee) {
            const float m = fmaf(q, wl[((d * 2 + 0) * DIM + ee) * ODIM + o],
                                 p * wl[((d * 2 + 1) * DIM + ee) * ODIM + o]);
            acc = fmaf(vl[d] * rv[ee], m, acc);
        }
    }
    out[idx] = acc;
}

extern "C" void kernel_launch(void* const* d_in, const int* in_sizes, int n_in,
                              void* d_out, int out_size, void* d_ws, size_t ws_size,
                              hipStream_t stream) {
    const float* x     = (const float*)d_in[0];
    const float* w0    = (const float*)d_in[1];
    const float* Wl    = (const float*)d_in[2];
    const float* wlab  = (const float*)d_in[3];
    const float* Wr    = (const float*)d_in[4];
    const float* wlast = (const float*)d_in[5];
    float* out = (float*)d_out;

    float* VL = (float*)d_ws;                 // 16384*8 floats
    float* RV = VL + 16384 * DIM;             // 16384*8 floats (1 MB total)

    mps_main<<<1024, 256, 0, stream>>>(x, w0, Wl, Wr, wlast, VL, RV);
    mps_combine<<<16384 * ODIM / 256, 256, 0, stream>>>(x, wlab, VL, RV, out);
}